// Round 18
// baseline (136.900 us; speedup 1.0000x reference)
//
#include <hip/hip_runtime.h>
#include <stdint.h>

#define B_TOT 16384
#define IN_DIM 128
#define H1 256
#define H2 128
#define NC 10

// LDS byte layout (identical to r7/r12):
//   W2T [256][128] f32 (131072) | WoT [128][10] f32 (5120) | 16x1KB scratch
#define W2T_BYTES (H1 * H2 * 4)            // 131072
#define WOT_OFF   W2T_BYTES
#define WOT_BYTES (H2 * NC * 4)            // 5120
#define SCR_OFF   (WOT_OFF + WOT_BYTES)    // 136192
#define LDS_BYTES (SCR_OFF + 16 * 1024)    // 152576

typedef float v2f __attribute__((ext_vector_type(2)));

// ---------------------------------------------------------------------------
// Kernel A (fused): blocks 0..1023 = cur1 GEMM; block 1024 = W2/Wo transpose.
// GEMM thread-tiling: 2 neurons (n, n+128) x 8 rows per thread ->
// per k-chunk: 2 W1 global b128 + 8 broadcast LDS b128 + 64 FMA
// (8 FMA per LDS read; r2's layout was 4). Per-(row,neuron) fmaf chain
// is k-ascending float4, bias last — bit-identical to the r2 gemm.
// ---------------------------------------------------------------------------
__global__ __launch_bounds__(256) void gemm1_fused_kernel(
    const float* __restrict__ x, const float* __restrict__ W1,
    const float* __restrict__ b1, const float* __restrict__ W2,
    const float* __restrict__ Wo, float* __restrict__ cur1,
    float* __restrict__ W2T, float* __restrict__ WoT) {
  const int tid = threadIdx.x;
  if (blockIdx.x == 1024) {  // transpose block (coalesced read, tiny)
    for (int idx = tid; idx < H2 * H1; idx += 256) {
      W2T[(idx & 255) * H2 + (idx >> 8)] = W2[idx];
    }
    for (int idx = tid; idx < NC * H2; idx += 256) {
      WoT[(idx & 127) * NC + (idx >> 7)] = Wo[idx];
    }
    return;
  }

  __shared__ float xs[16 * 128];  // 8 KB
  const long row0 = (long)blockIdx.x * 16;

  const float4* xt = (const float4*)(x + row0 * IN_DIM);
  float4* xs4 = (float4*)xs;
  xs4[tid] = xt[tid];
  xs4[tid + 256] = xt[tid + 256];
  __syncthreads();

  const int n0 = tid & 127;       // neuron pair (n0, n0+128)
  const int rb = (tid >> 7) * 8;  // rows rb..rb+7

  float acc0[8], acc1[8];
#pragma unroll
  for (int r = 0; r < 8; ++r) {
    acc0[r] = 0.f;
    acc1[r] = 0.f;
  }

  const float* wa = W1 + n0 * IN_DIM;
  const float* wb = W1 + (n0 + 128) * IN_DIM;

  for (int k0 = 0; k0 < IN_DIM; k0 += 4) {
    const float4 w0 = *(const float4*)(wa + k0);
    const float4 w1 = *(const float4*)(wb + k0);
#pragma unroll
    for (int r = 0; r < 8; ++r) {
      const float4 xv = *(const float4*)(xs + (rb + r) * IN_DIM + k0);
      acc0[r] = fmaf(w0.x, xv.x, acc0[r]);
      acc0[r] = fmaf(w0.y, xv.y, acc0[r]);
      acc0[r] = fmaf(w0.z, xv.z, acc0[r]);
      acc0[r] = fmaf(w0.w, xv.w, acc0[r]);
      acc1[r] = fmaf(w1.x, xv.x, acc1[r]);
      acc1[r] = fmaf(w1.y, xv.y, acc1[r]);
      acc1[r] = fmaf(w1.z, xv.z, acc1[r]);
      acc1[r] = fmaf(w1.w, xv.w, acc1[r]);
    }
  }
  const float bias0 = b1[n0];
  const float bias1 = b1[n0 + 128];
#pragma unroll
  for (int r = 0; r < 8; ++r) {
    float* op = cur1 + (row0 + rb + r) * H1;
    op[n0] = acc0[r] + bias0;
    op[n0 + 128] = acc1[r] + bias1;
  }
}

__device__ __forceinline__ int mbcnt64(unsigned long long m) {
  return (int)__builtin_amdgcn_mbcnt_hi(
      (unsigned)(m >> 32), __builtin_amdgcn_mbcnt_lo((unsigned)m, 0u));
}

// Bit-exact serial fallback (groups ascending, j ascending) — only taken
// when a row has >128 spikes in one step (probabilistically never).
__device__ __noinline__ v2f serial_row(unsigned long long m0,
                                       unsigned long long m1,
                                       unsigned long long m2,
                                       unsigned long long m3,
                                       const char* w2b) {
  v2f acc = {0.f, 0.f};
  while (m0) { const int j = (int)__builtin_ctzll(m0); m0 &= m0 - 1;
    acc += *(const v2f*)(w2b + (j << 9)); }
  while (m1) { const int j = (int)__builtin_ctzll(m1); m1 &= m1 - 1;
    acc += *(const v2f*)(w2b + ((64 + j) << 9)); }
  while (m2) { const int j = (int)__builtin_ctzll(m2); m2 &= m2 - 1;
    acc += *(const v2f*)(w2b + ((128 + j) << 9)); }
  while (m3) { const int j = (int)__builtin_ctzll(m3); m3 &= m3 - 1;
    acc += *(const v2f*)(w2b + ((192 + j) << 9)); }
  return acc;
}

// ---------------------------------------------------------------------------
// Kernel B: fused 20-step recurrent SNN — r12 VERBATIM (verified 90.3us,
// 48 VGPR, no spill). 256 persistent blocks (1/CU), 16 waves/block, 4
// rows/wave as TWO interleaved pairs. Rank-compacted int byte-offset
// lists, 8-wide ds_read_b64 clusters + exact 4/2/1 tails, no padding.
// Addend order per row: groups 0..3 ascending, j ascending, bias last;
// output layer evens-then-odds — bit-identical to r2/r7.
// ---------------------------------------------------------------------------
__global__ __launch_bounds__(1024) void snn_kernel(
    const float* __restrict__ cur1, const float* __restrict__ W2Tg,
    const float* __restrict__ WoTg, const float* __restrict__ b2,
    const float* __restrict__ bo, const int* __restrict__ nsp,
    float* __restrict__ out) {
  extern __shared__ float lds[];

  const int tid = threadIdx.x;
  {
    float4* dst = (float4*)lds;
    const float4* src = (const float4*)W2Tg;
#pragma unroll
    for (int i = 0; i < 8; ++i) dst[tid + i * 1024] = src[tid + i * 1024];
    if (tid < 320)
      ((float4*)((char*)lds + WOT_OFF))[tid] = ((const float4*)WoTg)[tid];
  }
  __syncthreads();

  const int w = tid >> 6;
  const int l = tid & 63;
  const int lo = (l < NC) ? l : 0;
  const float bb0 = b2[2 * l];
  const float bb1 = b2[2 * l + 1];
  const float bol = bo[lo];
  const int nsteps = *nsp;

  int* scrA = (int*)((char*)lds + SCR_OFF) + w * 256;  // 128 ints
  int* scrB = scrA + 128;                              // 128 ints
  const char* w2b = (const char*)lds + 8 * l;
  const char* wob = (const char*)lds + WOT_OFF + 4 * lo;

  const int wr0 = l << 9;
  const int wr1 = (64 + l) << 9;
  const int wr2 = (128 + l) << 9;
  const int wr3 = (192 + l) << 9;
  const int or0 = 80 * l;
  const int or1 = 80 * l + 40;

#define LOAD8(P, scrp, kk)                                  \
  const int4 P##ia = *(const int4*)((scrp) + (kk));         \
  const int4 P##ib = *(const int4*)((scrp) + (kk) + 4);     \
  const v2f P##p0 = *(const v2f*)(w2b + P##ia.x);           \
  const v2f P##p1 = *(const v2f*)(w2b + P##ia.y);           \
  const v2f P##p2 = *(const v2f*)(w2b + P##ia.z);           \
  const v2f P##p3 = *(const v2f*)(w2b + P##ia.w);           \
  const v2f P##p4 = *(const v2f*)(w2b + P##ib.x);           \
  const v2f P##p5 = *(const v2f*)(w2b + P##ib.y);           \
  const v2f P##p6 = *(const v2f*)(w2b + P##ib.z);           \
  const v2f P##p7 = *(const v2f*)(w2b + P##ib.w);

#define ADD8(P, acc)                                        \
  acc += P##p0; acc += P##p1; acc += P##p2; acc += P##p3;   \
  acc += P##p4; acc += P##p5; acc += P##p6; acc += P##p7;

#define TAILS(scrp, S, acc)                                 \
  {                                                         \
    int k = ((S) >> 3) << 3;                                \
    if ((S) & 4) {                                          \
      const int4 ia = *(const int4*)((scrp) + k);           \
      const v2f p0 = *(const v2f*)(w2b + ia.x);             \
      const v2f p1 = *(const v2f*)(w2b + ia.y);             \
      const v2f p2 = *(const v2f*)(w2b + ia.z);             \
      const v2f p3 = *(const v2f*)(w2b + ia.w);             \
      acc += p0; acc += p1; acc += p2; acc += p3;           \
      k += 4;                                               \
    }                                                       \
    if ((S) & 2) {                                          \
      const int2 ia = *(const int2*)((scrp) + k);           \
      const v2f p0 = *(const v2f*)(w2b + ia.x);             \
      const v2f p1 = *(const v2f*)(w2b + ia.y);             \
      acc += p0; acc += p1;                                 \
      k += 2;                                               \
    }                                                       \
    if ((S) & 1) {                                          \
      const v2f p0 = *(const v2f*)(w2b + (scrp)[k]);        \
      acc += p0;                                            \
    }                                                       \
  }

#define OLOAD8(P, scrp, kk)                                 \
  const int4 P##ia = *(const int4*)((scrp) + (kk));         \
  const int4 P##ib = *(const int4*)((scrp) + (kk) + 4);     \
  const float P##q0 = *(const float*)(wob + P##ia.x);       \
  const float P##q1 = *(const float*)(wob + P##ia.y);       \
  const float P##q2 = *(const float*)(wob + P##ia.z);       \
  const float P##q3 = *(const float*)(wob + P##ia.w);       \
  const float P##q4 = *(const float*)(wob + P##ib.x);       \
  const float P##q5 = *(const float*)(wob + P##ib.y);       \
  const float P##q6 = *(const float*)(wob + P##ib.z);       \
  const float P##q7 = *(const float*)(wob + P##ib.w);

#define OADD8(P, co)                                        \
  co += P##q0; co += P##q1; co += P##q2; co += P##q3;       \
  co += P##q4; co += P##q5; co += P##q6; co += P##q7;

#define OTAILS(scrp, S, co)                                 \
  {                                                         \
    int k = ((S) >> 3) << 3;                                \
    if ((S) & 4) {                                          \
      const int4 ia = *(const int4*)((scrp) + k);           \
      const float u0 = *(const float*)(wob + ia.x);         \
      const float u1 = *(const float*)(wob + ia.y);         \
      const float u2 = *(const float*)(wob + ia.z);         \
      const float u3 = *(const float*)(wob + ia.w);         \
      co += u0; co += u1; co += u2; co += u3;               \
      k += 4;                                               \
    }                                                       \
    if ((S) & 2) {                                          \
      const int2 ia = *(const int2*)((scrp) + k);           \
      const float u0 = *(const float*)(wob + ia.x);         \
      const float u1 = *(const float*)(wob + ia.y);         \
      co += u0; co += u1;                                   \
      k += 2;                                               \
    }                                                       \
    if ((S) & 1) {                                          \
      co += *(const float*)(wob + (scrp)[k]);               \
    }                                                       \
  }

  for (int rp = 0; rp < 2; ++rp) {
    const long bA = (long)blockIdx.x * 64 + w * 4 + rp * 2;
    const long bB = bA + 1;

    float cA[4], cB[4];
#pragma unroll
    for (int i = 0; i < 4; ++i) {
      cA[i] = cur1[bA * H1 + i * 64 + l];
      cB[i] = cur1[bB * H1 + i * 64 + l];
    }

    float mA1[4] = {0.f, 0.f, 0.f, 0.f}, spA1[4] = {0.f, 0.f, 0.f, 0.f};
    float mB1[4] = {0.f, 0.f, 0.f, 0.f}, spB1[4] = {0.f, 0.f, 0.f, 0.f};
    float mA2a = 0.f, mA2b = 0.f, spA2a = 0.f, spA2b = 0.f;
    float mB2a = 0.f, mB2b = 0.f, spB2a = 0.f, spB2b = 0.f;
    float moA = 0.f, spoA = 0.f, cntA = 0.f;
    float moB = 0.f, spoB = 0.f, cntB = 0.f;

    for (int t = 0; t < nsteps; ++t) {
      // ---- layer 1 LIF + spike masks, both rows ----
      unsigned long long gA[4], gB[4];
      bool sA[4], sB[4];
#pragma unroll
      for (int i = 0; i < 4; ++i) {
        mA1[i] = fmaf(0.5f, mA1[i], cA[i]) - spA1[i];
        sA[i] = mA1[i] > 1.0f;
        spA1[i] = sA[i] ? 1.0f : 0.0f;
        gA[i] = __ballot(sA[i]);
        mB1[i] = fmaf(0.5f, mB1[i], cB[i]) - spB1[i];
        sB[i] = mB1[i] > 1.0f;
        spB1[i] = sB[i] ? 1.0f : 0.0f;
        gB[i] = __ballot(sB[i]);
      }
      const int pA0 = (int)__popcll(gA[0]);
      const int pA01 = pA0 + (int)__popcll(gA[1]);
      const int pA012 = pA01 + (int)__popcll(gA[2]);
      const int SA = pA012 + (int)__popcll(gA[3]);
      const int pB0 = (int)__popcll(gB[0]);
      const int pB01 = pB0 + (int)__popcll(gB[1]);
      const int pB012 = pB01 + (int)__popcll(gB[2]);
      const int SB = pB012 + (int)__popcll(gB[3]);

      // ---- build both lists (rank-compacted, j-ascending; capped) ----
      if (sA[0]) scrA[mbcnt64(gA[0])] = wr0;
      if (sA[1]) scrA[pA0 + mbcnt64(gA[1])] = wr1;
      if (sA[2]) { const int rk = pA01 + mbcnt64(gA[2]);
                   if (rk < 128) scrA[rk] = wr2; }
      if (sA[3]) { const int rk = pA012 + mbcnt64(gA[3]);
                   if (rk < 128) scrA[rk] = wr3; }
      if (sB[0]) scrB[mbcnt64(gB[0])] = wr0;
      if (sB[1]) scrB[pB0 + mbcnt64(gB[1])] = wr1;
      if (sB[2]) { const int rk = pB01 + mbcnt64(gB[2]);
                   if (rk < 128) scrB[rk] = wr2; }
      if (sB[3]) { const int rk = pB012 + mbcnt64(gB[3]);
                   if (rk < 128) scrB[rk] = wr3; }
      asm volatile("s_waitcnt lgkmcnt(0)" ::: "memory");

      // ---- cur2: interleaved 8-wide clusters + exact 4/2/1 tails ----
      v2f accA = {0.f, 0.f}, accB = {0.f, 0.f};
      if (__builtin_expect(SA > 128 || SB > 128, 0)) {
        accA = serial_row(gA[0], gA[1], gA[2], gA[3], w2b);
        accB = serial_row(gB[0], gB[1], gB[2], gB[3], w2b);
      } else {
        const int nA8 = SA >> 3;
        const int nB8 = SB >> 3;
        int ka = 0, kb = 0;
        while (ka < nA8 && kb < nB8) {
          { LOAD8(a_, scrA, ka * 8) LOAD8(b_, scrB, kb * 8)
            ADD8(a_, accA) ADD8(b_, accB) }
          ++ka; ++kb;
        }
        while (ka < nA8) {
          { LOAD8(c_, scrA, ka * 8) ADD8(c_, accA) }
          ++ka;
        }
        while (kb < nB8) {
          { LOAD8(d_, scrB, kb * 8) ADD8(d_, accB) }
          ++kb;
        }
        TAILS(scrA, SA, accA)
        TAILS(scrB, SB, accB)
      }
      const float aA0 = accA.x + bb0;
      const float aA1 = accA.y + bb1;
      const float aB0 = accB.x + bb0;
      const float aB1 = accB.y + bb1;

      // ---- layer 2 LIF, both rows ----
      mA2a = fmaf(0.5f, mA2a, aA0) - spA2a;
      mA2b = fmaf(0.5f, mA2b, aA1) - spA2b;
      mB2a = fmaf(0.5f, mB2a, aB0) - spB2a;
      mB2b = fmaf(0.5f, mB2b, aB1) - spB2b;
      const bool saA = mA2a > 1.0f, sbA = mA2b > 1.0f;
      const bool saB = mB2a > 1.0f, sbB = mB2b > 1.0f;
      const unsigned long long mAe = __ballot(saA);
      const unsigned long long mAo = __ballot(sbA);
      const unsigned long long mBe = __ballot(saB);
      const unsigned long long mBo = __ballot(sbB);
      spA2a = saA ? 1.0f : 0.0f;
      spA2b = sbA ? 1.0f : 0.0f;
      spB2a = saB ? 1.0f : 0.0f;
      spB2b = sbB ? 1.0f : 0.0f;
      const int pAe = (int)__popcll(mAe);
      const int SoA = pAe + (int)__popcll(mAo);
      const int pBe = (int)__popcll(mBe);
      const int SoB = pBe + (int)__popcll(mBo);

      // ---- output-layer lists (evens ascending, then odds; max 128) ----
      if (saA) scrA[mbcnt64(mAe)] = or0;
      if (sbA) scrA[pAe + mbcnt64(mAo)] = or1;
      if (saB) scrB[mbcnt64(mBe)] = or0;
      if (sbB) scrB[pBe + mbcnt64(mBo)] = or1;
      asm volatile("s_waitcnt lgkmcnt(0)" ::: "memory");

      float coA = 0.f, coB = 0.f;
      {
        const int nA8 = SoA >> 3;
        const int nB8 = SoB >> 3;
        int ka = 0, kb = 0;
        while (ka < nA8 && kb < nB8) {
          { OLOAD8(e_, scrA, ka * 8) OLOAD8(f_, scrB, kb * 8)
            OADD8(e_, coA) OADD8(f_, coB) }
          ++ka; ++kb;
        }
        while (ka < nA8) {
          { OLOAD8(g_, scrA, ka * 8) OADD8(g_, coA) }
          ++ka;
        }
        while (kb < nB8) {
          { OLOAD8(h_, scrB, kb * 8) OADD8(h_, coB) }
          ++kb;
        }
        OTAILS(scrA, SoA, coA)
        OTAILS(scrB, SoB, coB)
      }
      coA += bol;
      coB += bol;

      // ---- output LIF + spike count, both rows ----
      moA = fmaf(0.5f, moA, coA) - spoA;
      moB = fmaf(0.5f, moB, coB) - spoB;
      const bool soA = moA > 1.0f;
      const bool soB = moB > 1.0f;
      spoA = soA ? 1.0f : 0.0f;
      spoB = soB ? 1.0f : 0.0f;
      cntA += spoA;
      cntB += spoB;
    }

    if (l < NC) {
      out[bA * NC + l] = cntA;
      out[bB * NC + l] = cntB;
    }
  }
#undef LOAD8
#undef ADD8
#undef TAILS
#undef OLOAD8
#undef OADD8
#undef OTAILS
}

// ---------------------------------------------------------------------------
extern "C" void kernel_launch(void* const* d_in, const int* in_sizes, int n_in,
                              void* d_out, int out_size, void* d_ws,
                              size_t ws_size, hipStream_t stream) {
  const float* x  = (const float*)d_in[0];
  const float* W1 = (const float*)d_in[1];
  const float* b1 = (const float*)d_in[2];
  const float* W2 = (const float*)d_in[3];
  const float* b2 = (const float*)d_in[4];
  const float* Wo = (const float*)d_in[5];
  const float* bo = (const float*)d_in[6];
  const int* nsp  = (const int*)d_in[7];
  float* outp = (float*)d_out;

  // ws layout: cur1 (16384*256 f) | W2T (32768 f) | WoT (1280 f)
  float* cur1 = (float*)d_ws;
  float* W2Tg = cur1 + (size_t)B_TOT * H1;
  float* WoTg = W2Tg + H1 * H2;

  gemm1_fused_kernel<<<B_TOT / 16 + 1, 256, 0, stream>>>(x, W1, b1, W2, Wo,
                                                         cur1, W2Tg, WoTg);

  hipFuncSetAttribute((const void*)snn_kernel,
                      hipFuncAttributeMaxDynamicSharedMemorySize, LDS_BYTES);
  snn_kernel<<<256, 1024, LDS_BYTES, stream>>>(cur1, W2Tg, WoTg, b2, bo, nsp,
                                               outp);
}

// Round 19
// 128.752 us; speedup vs baseline: 1.0633x; 1.0633x over previous
//
#include <hip/hip_runtime.h>
#include <stdint.h>

#define B_TOT 16384
#define IN_DIM 128
#define H1 256
#define H2 128
#define NC 10

// LDS byte layout (identical to r7/r12):
//   W2T [256][128] f32 (131072) | WoT [128][10] f32 (5120) | 16x1KB scratch
#define W2T_BYTES (H1 * H2 * 4)            // 131072
#define WOT_OFF   W2T_BYTES
#define WOT_BYTES (H2 * NC * 4)            // 5120
#define SCR_OFF   (WOT_OFF + WOT_BYTES)    // 136192
#define LDS_BYTES (SCR_OFF + 16 * 1024)    // 152576

typedef float v2f __attribute__((ext_vector_type(2)));

// ---------------------------------------------------------------------------
// Kernel A: cur1 GEMM, 2 neurons (n, n+128) x 8 rows per thread ->
// per k-chunk: 2 W1 global b128 + 8 broadcast LDS b128 + 64 FMA
// (8 FMA per LDS read; r2's layout was 4). Per-(row,neuron) fmaf chain
// is k-ascending float4, bias last — bit-identical to the r2 gemm
// (verified absmax 0.0 in r18).
// ---------------------------------------------------------------------------
__global__ __launch_bounds__(256) void gemm1_kernel(
    const float* __restrict__ x, const float* __restrict__ W1,
    const float* __restrict__ b1, float* __restrict__ cur1) {
  __shared__ float xs[16 * 128];  // 8 KB
  const int tid = threadIdx.x;
  const long row0 = (long)blockIdx.x * 16;

  const float4* xt = (const float4*)(x + row0 * IN_DIM);
  float4* xs4 = (float4*)xs;
  xs4[tid] = xt[tid];
  xs4[tid + 256] = xt[tid + 256];
  __syncthreads();

  const int n0 = tid & 127;       // neuron pair (n0, n0+128)
  const int rb = (tid >> 7) * 8;  // rows rb..rb+7

  float acc0[8], acc1[8];
#pragma unroll
  for (int r = 0; r < 8; ++r) {
    acc0[r] = 0.f;
    acc1[r] = 0.f;
  }

  const float* wa = W1 + n0 * IN_DIM;
  const float* wb = W1 + (n0 + 128) * IN_DIM;

  for (int k0 = 0; k0 < IN_DIM; k0 += 4) {
    const float4 w0 = *(const float4*)(wa + k0);
    const float4 w1 = *(const float4*)(wb + k0);
#pragma unroll
    for (int r = 0; r < 8; ++r) {
      const float4 xv = *(const float4*)(xs + (rb + r) * IN_DIM + k0);
      acc0[r] = fmaf(w0.x, xv.x, acc0[r]);
      acc0[r] = fmaf(w0.y, xv.y, acc0[r]);
      acc0[r] = fmaf(w0.z, xv.z, acc0[r]);
      acc0[r] = fmaf(w0.w, xv.w, acc0[r]);
      acc1[r] = fmaf(w1.x, xv.x, acc1[r]);
      acc1[r] = fmaf(w1.y, xv.y, acc1[r]);
      acc1[r] = fmaf(w1.z, xv.z, acc1[r]);
      acc1[r] = fmaf(w1.w, xv.w, acc1[r]);
    }
  }
  const float bias0 = b1[n0];
  const float bias1 = b1[n0 + 128];
#pragma unroll
  for (int r = 0; r < 8; ++r) {
    float* op = cur1 + (row0 + rb + r) * H1;
    op[n0] = acc0[r] + bias0;
    op[n0 + 128] = acc1[r] + bias1;
  }
}

// ---------------------------------------------------------------------------
// Kernel A2: W2 -> W2T (256x128), Wo -> WoT into workspace.  (r2 version —
// 9 blocks x 1024 threads, spreads scattered stores across CUs)
// ---------------------------------------------------------------------------
__global__ __launch_bounds__(1024) void transpose_kernel(
    const float* __restrict__ W2, const float* __restrict__ Wo,
    float* __restrict__ W2T, float* __restrict__ WoT) {
  const int idx = blockIdx.x * 1024 + threadIdx.x;
  if (idx < H2 * H1) {
    const int o = idx >> 8;
    const int j = idx & 255;
    W2T[j * H2 + o] = W2[idx];
  } else {
    const int k = idx - H2 * H1;
    if (k < NC * H2) {
      const int o = k >> 7;
      const int j = k & 127;
      WoT[j * NC + o] = Wo[k];
    }
  }
}

__device__ __forceinline__ int mbcnt64(unsigned long long m) {
  return (int)__builtin_amdgcn_mbcnt_hi(
      (unsigned)(m >> 32), __builtin_amdgcn_mbcnt_lo((unsigned)m, 0u));
}

// Bit-exact serial fallback (groups ascending, j ascending) — only taken
// when a row has >128 spikes in one step (probabilistically never).
__device__ __noinline__ v2f serial_row(unsigned long long m0,
                                       unsigned long long m1,
                                       unsigned long long m2,
                                       unsigned long long m3,
                                       const char* w2b) {
  v2f acc = {0.f, 0.f};
  while (m0) { const int j = (int)__builtin_ctzll(m0); m0 &= m0 - 1;
    acc += *(const v2f*)(w2b + (j << 9)); }
  while (m1) { const int j = (int)__builtin_ctzll(m1); m1 &= m1 - 1;
    acc += *(const v2f*)(w2b + ((64 + j) << 9)); }
  while (m2) { const int j = (int)__builtin_ctzll(m2); m2 &= m2 - 1;
    acc += *(const v2f*)(w2b + ((128 + j) << 9)); }
  while (m3) { const int j = (int)__builtin_ctzll(m3); m3 &= m3 - 1;
    acc += *(const v2f*)(w2b + ((192 + j) << 9)); }
  return acc;
}

// ---------------------------------------------------------------------------
// Kernel B: fused 20-step recurrent SNN — r12 VERBATIM (verified 90.3us,
// 48 VGPR, no spill). 256 persistent blocks (1/CU), 16 waves/block, 4
// rows/wave as TWO interleaved pairs. Rank-compacted int byte-offset
// lists, 8-wide ds_read_b64 clusters + exact 4/2/1 tails, no padding.
// Addend order per row: groups 0..3 ascending, j ascending, bias last;
// output layer evens-then-odds — bit-identical to r2/r7.
// ---------------------------------------------------------------------------
__global__ __launch_bounds__(1024) void snn_kernel(
    const float* __restrict__ cur1, const float* __restrict__ W2Tg,
    const float* __restrict__ WoTg, const float* __restrict__ b2,
    const float* __restrict__ bo, const int* __restrict__ nsp,
    float* __restrict__ out) {
  extern __shared__ float lds[];

  const int tid = threadIdx.x;
  {
    float4* dst = (float4*)lds;
    const float4* src = (const float4*)W2Tg;
#pragma unroll
    for (int i = 0; i < 8; ++i) dst[tid + i * 1024] = src[tid + i * 1024];
    if (tid < 320)
      ((float4*)((char*)lds + WOT_OFF))[tid] = ((const float4*)WoTg)[tid];
  }
  __syncthreads();

  const int w = tid >> 6;
  const int l = tid & 63;
  const int lo = (l < NC) ? l : 0;
  const float bb0 = b2[2 * l];
  const float bb1 = b2[2 * l + 1];
  const float bol = bo[lo];
  const int nsteps = *nsp;

  int* scrA = (int*)((char*)lds + SCR_OFF) + w * 256;  // 128 ints
  int* scrB = scrA + 128;                              // 128 ints
  const char* w2b = (const char*)lds + 8 * l;
  const char* wob = (const char*)lds + WOT_OFF + 4 * lo;

  const int wr0 = l << 9;
  const int wr1 = (64 + l) << 9;
  const int wr2 = (128 + l) << 9;
  const int wr3 = (192 + l) << 9;
  const int or0 = 80 * l;
  const int or1 = 80 * l + 40;

#define LOAD8(P, scrp, kk)                                  \
  const int4 P##ia = *(const int4*)((scrp) + (kk));         \
  const int4 P##ib = *(const int4*)((scrp) + (kk) + 4);     \
  const v2f P##p0 = *(const v2f*)(w2b + P##ia.x);           \
  const v2f P##p1 = *(const v2f*)(w2b + P##ia.y);           \
  const v2f P##p2 = *(const v2f*)(w2b + P##ia.z);           \
  const v2f P##p3 = *(const v2f*)(w2b + P##ia.w);           \
  const v2f P##p4 = *(const v2f*)(w2b + P##ib.x);           \
  const v2f P##p5 = *(const v2f*)(w2b + P##ib.y);           \
  const v2f P##p6 = *(const v2f*)(w2b + P##ib.z);           \
  const v2f P##p7 = *(const v2f*)(w2b + P##ib.w);

#define ADD8(P, acc)                                        \
  acc += P##p0; acc += P##p1; acc += P##p2; acc += P##p3;   \
  acc += P##p4; acc += P##p5; acc += P##p6; acc += P##p7;

#define TAILS(scrp, S, acc)                                 \
  {                                                         \
    int k = ((S) >> 3) << 3;                                \
    if ((S) & 4) {                                          \
      const int4 ia = *(const int4*)((scrp) + k);           \
      const v2f p0 = *(const v2f*)(w2b + ia.x);             \
      const v2f p1 = *(const v2f*)(w2b + ia.y);             \
      const v2f p2 = *(const v2f*)(w2b + ia.z);             \
      const v2f p3 = *(const v2f*)(w2b + ia.w);             \
      acc += p0; acc += p1; acc += p2; acc += p3;           \
      k += 4;                                               \
    }                                                       \
    if ((S) & 2) {                                          \
      const int2 ia = *(const int2*)((scrp) + k);           \
      const v2f p0 = *(const v2f*)(w2b + ia.x);             \
      const v2f p1 = *(const v2f*)(w2b + ia.y);             \
      acc += p0; acc += p1;                                 \
      k += 2;                                               \
    }                                                       \
    if ((S) & 1) {                                          \
      const v2f p0 = *(const v2f*)(w2b + (scrp)[k]);        \
      acc += p0;                                            \
    }                                                       \
  }

#define OLOAD8(P, scrp, kk)                                 \
  const int4 P##ia = *(const int4*)((scrp) + (kk));         \
  const int4 P##ib = *(const int4*)((scrp) + (kk) + 4);     \
  const float P##q0 = *(const float*)(wob + P##ia.x);       \
  const float P##q1 = *(const float*)(wob + P##ia.y);       \
  const float P##q2 = *(const float*)(wob + P##ia.z);       \
  const float P##q3 = *(const float*)(wob + P##ia.w);       \
  const float P##q4 = *(const float*)(wob + P##ib.x);       \
  const float P##q5 = *(const float*)(wob + P##ib.y);       \
  const float P##q6 = *(const float*)(wob + P##ib.z);       \
  const float P##q7 = *(const float*)(wob + P##ib.w);

#define OADD8(P, co)                                        \
  co += P##q0; co += P##q1; co += P##q2; co += P##q3;       \
  co += P##q4; co += P##q5; co += P##q6; co += P##q7;

#define OTAILS(scrp, S, co)                                 \
  {                                                         \
    int k = ((S) >> 3) << 3;                                \
    if ((S) & 4) {                                          \
      const int4 ia = *(const int4*)((scrp) + k);           \
      const float u0 = *(const float*)(wob + ia.x);         \
      const float u1 = *(const float*)(wob + ia.y);         \
      const float u2 = *(const float*)(wob + ia.z);         \
      const float u3 = *(const float*)(wob + ia.w);         \
      co += u0; co += u1; co += u2; co += u3;               \
      k += 4;                                               \
    }                                                       \
    if ((S) & 2) {                                          \
      const int2 ia = *(const int2*)((scrp) + k);           \
      const float u0 = *(const float*)(wob + ia.x);         \
      const float u1 = *(const float*)(wob + ia.y);         \
      co += u0; co += u1;                                   \
      k += 2;                                               \
    }                                                       \
    if ((S) & 1) {                                          \
      co += *(const float*)(wob + (scrp)[k]);               \
    }                                                       \
  }

  for (int rp = 0; rp < 2; ++rp) {
    const long bA = (long)blockIdx.x * 64 + w * 4 + rp * 2;
    const long bB = bA + 1;

    float cA[4], cB[4];
#pragma unroll
    for (int i = 0; i < 4; ++i) {
      cA[i] = cur1[bA * H1 + i * 64 + l];
      cB[i] = cur1[bB * H1 + i * 64 + l];
    }

    float mA1[4] = {0.f, 0.f, 0.f, 0.f}, spA1[4] = {0.f, 0.f, 0.f, 0.f};
    float mB1[4] = {0.f, 0.f, 0.f, 0.f}, spB1[4] = {0.f, 0.f, 0.f, 0.f};
    float mA2a = 0.f, mA2b = 0.f, spA2a = 0.f, spA2b = 0.f;
    float mB2a = 0.f, mB2b = 0.f, spB2a = 0.f, spB2b = 0.f;
    float moA = 0.f, spoA = 0.f, cntA = 0.f;
    float moB = 0.f, spoB = 0.f, cntB = 0.f;

    for (int t = 0; t < nsteps; ++t) {
      // ---- layer 1 LIF + spike masks, both rows ----
      unsigned long long gA[4], gB[4];
      bool sA[4], sB[4];
#pragma unroll
      for (int i = 0; i < 4; ++i) {
        mA1[i] = fmaf(0.5f, mA1[i], cA[i]) - spA1[i];
        sA[i] = mA1[i] > 1.0f;
        spA1[i] = sA[i] ? 1.0f : 0.0f;
        gA[i] = __ballot(sA[i]);
        mB1[i] = fmaf(0.5f, mB1[i], cB[i]) - spB1[i];
        sB[i] = mB1[i] > 1.0f;
        spB1[i] = sB[i] ? 1.0f : 0.0f;
        gB[i] = __ballot(sB[i]);
      }
      const int pA0 = (int)__popcll(gA[0]);
      const int pA01 = pA0 + (int)__popcll(gA[1]);
      const int pA012 = pA01 + (int)__popcll(gA[2]);
      const int SA = pA012 + (int)__popcll(gA[3]);
      const int pB0 = (int)__popcll(gB[0]);
      const int pB01 = pB0 + (int)__popcll(gB[1]);
      const int pB012 = pB01 + (int)__popcll(gB[2]);
      const int SB = pB012 + (int)__popcll(gB[3]);

      // ---- build both lists (rank-compacted, j-ascending; capped) ----
      if (sA[0]) scrA[mbcnt64(gA[0])] = wr0;
      if (sA[1]) scrA[pA0 + mbcnt64(gA[1])] = wr1;
      if (sA[2]) { const int rk = pA01 + mbcnt64(gA[2]);
                   if (rk < 128) scrA[rk] = wr2; }
      if (sA[3]) { const int rk = pA012 + mbcnt64(gA[3]);
                   if (rk < 128) scrA[rk] = wr3; }
      if (sB[0]) scrB[mbcnt64(gB[0])] = wr0;
      if (sB[1]) scrB[pB0 + mbcnt64(gB[1])] = wr1;
      if (sB[2]) { const int rk = pB01 + mbcnt64(gB[2]);
                   if (rk < 128) scrB[rk] = wr2; }
      if (sB[3]) { const int rk = pB012 + mbcnt64(gB[3]);
                   if (rk < 128) scrB[rk] = wr3; }
      asm volatile("s_waitcnt lgkmcnt(0)" ::: "memory");

      // ---- cur2: interleaved 8-wide clusters + exact 4/2/1 tails ----
      v2f accA = {0.f, 0.f}, accB = {0.f, 0.f};
      if (__builtin_expect(SA > 128 || SB > 128, 0)) {
        accA = serial_row(gA[0], gA[1], gA[2], gA[3], w2b);
        accB = serial_row(gB[0], gB[1], gB[2], gB[3], w2b);
      } else {
        const int nA8 = SA >> 3;
        const int nB8 = SB >> 3;
        int ka = 0, kb = 0;
        while (ka < nA8 && kb < nB8) {
          { LOAD8(a_, scrA, ka * 8) LOAD8(b_, scrB, kb * 8)
            ADD8(a_, accA) ADD8(b_, accB) }
          ++ka; ++kb;
        }
        while (ka < nA8) {
          { LOAD8(c_, scrA, ka * 8) ADD8(c_, accA) }
          ++ka;
        }
        while (kb < nB8) {
          { LOAD8(d_, scrB, kb * 8) ADD8(d_, accB) }
          ++kb;
        }
        TAILS(scrA, SA, accA)
        TAILS(scrB, SB, accB)
      }
      const float aA0 = accA.x + bb0;
      const float aA1 = accA.y + bb1;
      const float aB0 = accB.x + bb0;
      const float aB1 = accB.y + bb1;

      // ---- layer 2 LIF, both rows ----
      mA2a = fmaf(0.5f, mA2a, aA0) - spA2a;
      mA2b = fmaf(0.5f, mA2b, aA1) - spA2b;
      mB2a = fmaf(0.5f, mB2a, aB0) - spB2a;
      mB2b = fmaf(0.5f, mB2b, aB1) - spB2b;
      const bool saA = mA2a > 1.0f, sbA = mA2b > 1.0f;
      const bool saB = mB2a > 1.0f, sbB = mB2b > 1.0f;
      const unsigned long long mAe = __ballot(saA);
      const unsigned long long mAo = __ballot(sbA);
      const unsigned long long mBe = __ballot(saB);
      const unsigned long long mBo = __ballot(sbB);
      spA2a = saA ? 1.0f : 0.0f;
      spA2b = sbA ? 1.0f : 0.0f;
      spB2a = saB ? 1.0f : 0.0f;
      spB2b = sbB ? 1.0f : 0.0f;
      const int pAe = (int)__popcll(mAe);
      const int SoA = pAe + (int)__popcll(mAo);
      const int pBe = (int)__popcll(mBe);
      const int SoB = pBe + (int)__popcll(mBo);

      // ---- output-layer lists (evens ascending, then odds; max 128) ----
      if (saA) scrA[mbcnt64(mAe)] = or0;
      if (sbA) scrA[pAe + mbcnt64(mAo)] = or1;
      if (saB) scrB[mbcnt64(mBe)] = or0;
      if (sbB) scrB[pBe + mbcnt64(mBo)] = or1;
      asm volatile("s_waitcnt lgkmcnt(0)" ::: "memory");

      float coA = 0.f, coB = 0.f;
      {
        const int nA8 = SoA >> 3;
        const int nB8 = SoB >> 3;
        int ka = 0, kb = 0;
        while (ka < nA8 && kb < nB8) {
          { OLOAD8(e_, scrA, ka * 8) OLOAD8(f_, scrB, kb * 8)
            OADD8(e_, coA) OADD8(f_, coB) }
          ++ka; ++kb;
        }
        while (ka < nA8) {
          { OLOAD8(g_, scrA, ka * 8) OADD8(g_, coA) }
          ++ka;
        }
        while (kb < nB8) {
          { OLOAD8(h_, scrB, kb * 8) OADD8(h_, coB) }
          ++kb;
        }
        OTAILS(scrA, SoA, coA)
        OTAILS(scrB, SoB, coB)
      }
      coA += bol;
      coB += bol;

      // ---- output LIF + spike count, both rows ----
      moA = fmaf(0.5f, moA, coA) - spoA;
      moB = fmaf(0.5f, moB, coB) - spoB;
      const bool soA = moA > 1.0f;
      const bool soB = moB > 1.0f;
      spoA = soA ? 1.0f : 0.0f;
      spoB = soB ? 1.0f : 0.0f;
      cntA += spoA;
      cntB += spoB;
    }

    if (l < NC) {
      out[bA * NC + l] = cntA;
      out[bB * NC + l] = cntB;
    }
  }
#undef LOAD8
#undef ADD8
#undef TAILS
#undef OLOAD8
#undef OADD8
#undef OTAILS
}

// ---------------------------------------------------------------------------
extern "C" void kernel_launch(void* const* d_in, const int* in_sizes, int n_in,
                              void* d_out, int out_size, void* d_ws,
                              size_t ws_size, hipStream_t stream) {
  const float* x  = (const float*)d_in[0];
  const float* W1 = (const float*)d_in[1];
  const float* b1 = (const float*)d_in[2];
  const float* W2 = (const float*)d_in[3];
  const float* b2 = (const float*)d_in[4];
  const float* Wo = (const float*)d_in[5];
  const float* bo = (const float*)d_in[6];
  const int* nsp  = (const int*)d_in[7];
  float* outp = (float*)d_out;

  // ws layout: cur1 (16384*256 f) | W2T (32768 f) | WoT (1280 f)
  float* cur1 = (float*)d_ws;
  float* W2Tg = cur1 + (size_t)B_TOT * H1;
  float* WoTg = W2Tg + H1 * H2;

  gemm1_kernel<<<B_TOT / 16, 256, 0, stream>>>(x, W1, b1, cur1);
  transpose_kernel<<<(H2 * H1 + NC * H2 + 1023) / 1024, 1024, 0, stream>>>(
      W2, Wo, W2Tg, WoTg);

  hipFuncSetAttribute((const void*)snn_kernel,
                      hipFuncAttributeMaxDynamicSharedMemorySize, LDS_BYTES);
  snn_kernel<<<256, 1024, LDS_BYTES, stream>>>(cur1, W2Tg, WoTg, b2, bo, nsp,
                                               outp);
}

// Round 20
// 115.399 us; speedup vs baseline: 1.1863x; 1.1157x over previous
//
#include <hip/hip_runtime.h>
#include <stdint.h>

#define B_TOT 16384
#define IN_DIM 128
#define H1 256
#define H2 128
#define NC 10

// LDS byte layout (identical to r7/r12):
//   W2T [256][128] f32 (131072) | WoT [128][10] f32 (5120) | 16x1KB scratch
#define W2T_BYTES (H1 * H2 * 4)            // 131072
#define WOT_OFF   W2T_BYTES
#define WOT_BYTES (H2 * NC * 4)            // 5120
#define SCR_OFF   (WOT_OFF + WOT_BYTES)    // 136192
#define LDS_BYTES (SCR_OFF + 16 * 1024)    // 152576

typedef float v2f __attribute__((ext_vector_type(2)));

// ---------------------------------------------------------------------------
// Kernel A: cur1[b][n] = sum_k x[b][k]*W1[n][k] + b1[n]   (r2 version —
// LDS-broadcast x tile, 1 thread = 1 W1 row (each row fetched once/block),
// verified ~20us; best of 5 gemm variants tried r2/r13/r15/r18/r19)
// ---------------------------------------------------------------------------
__global__ __launch_bounds__(256) void gemm1_kernel(
    const float* __restrict__ x, const float* __restrict__ W1,
    const float* __restrict__ b1, float* __restrict__ cur1) {
  __shared__ float xs[16 * 128];
  const int tid = threadIdx.x;
  const long row0 = (long)blockIdx.x * 16;

  const float4* xt = (const float4*)(x + row0 * IN_DIM);
  float4* xs4 = (float4*)xs;
  xs4[tid] = xt[tid];
  xs4[tid + 256] = xt[tid + 256];
  __syncthreads();

  const int n = tid;
  float acc[16];
#pragma unroll
  for (int r = 0; r < 16; ++r) acc[r] = 0.f;

  const float* wrow = W1 + n * IN_DIM;
  for (int k0 = 0; k0 < IN_DIM; k0 += 4) {
    const float4 wv = *(const float4*)(wrow + k0);
#pragma unroll
    for (int r = 0; r < 16; ++r) {
      const float4 xv = *(const float4*)(xs + r * IN_DIM + k0);
      acc[r] = fmaf(wv.x, xv.x, acc[r]);
      acc[r] = fmaf(wv.y, xv.y, acc[r]);
      acc[r] = fmaf(wv.z, xv.z, acc[r]);
      acc[r] = fmaf(wv.w, xv.w, acc[r]);
    }
  }
  const float bias = b1[n];
#pragma unroll
  for (int r = 0; r < 16; ++r)
    cur1[(row0 + r) * H1 + n] = acc[r] + bias;
}

// ---------------------------------------------------------------------------
// Kernel A2: W2 -> W2T (256x128), Wo -> WoT into workspace.  (r2 version)
// ---------------------------------------------------------------------------
__global__ __launch_bounds__(1024) void transpose_kernel(
    const float* __restrict__ W2, const float* __restrict__ Wo,
    float* __restrict__ W2T, float* __restrict__ WoT) {
  const int idx = blockIdx.x * 1024 + threadIdx.x;
  if (idx < H2 * H1) {
    const int o = idx >> 8;
    const int j = idx & 255;
    W2T[j * H2 + o] = W2[idx];
  } else {
    const int k = idx - H2 * H1;
    if (k < NC * H2) {
      const int o = k >> 7;
      const int j = k & 127;
      WoT[j * NC + o] = Wo[k];
    }
  }
}

__device__ __forceinline__ int mbcnt64(unsigned long long m) {
  return (int)__builtin_amdgcn_mbcnt_hi(
      (unsigned)(m >> 32), __builtin_amdgcn_mbcnt_lo((unsigned)m, 0u));
}

// Bit-exact serial fallback (groups ascending, j ascending) — only taken
// when a row has >128 spikes in one step (probabilistically never).
__device__ __noinline__ v2f serial_row(unsigned long long m0,
                                       unsigned long long m1,
                                       unsigned long long m2,
                                       unsigned long long m3,
                                       const char* w2b) {
  v2f acc = {0.f, 0.f};
  while (m0) { const int j = (int)__builtin_ctzll(m0); m0 &= m0 - 1;
    acc += *(const v2f*)(w2b + (j << 9)); }
  while (m1) { const int j = (int)__builtin_ctzll(m1); m1 &= m1 - 1;
    acc += *(const v2f*)(w2b + ((64 + j) << 9)); }
  while (m2) { const int j = (int)__builtin_ctzll(m2); m2 &= m2 - 1;
    acc += *(const v2f*)(w2b + ((128 + j) << 9)); }
  while (m3) { const int j = (int)__builtin_ctzll(m3); m3 &= m3 - 1;
    acc += *(const v2f*)(w2b + ((192 + j) << 9)); }
  return acc;
}

// ---------------------------------------------------------------------------
// Kernel B: fused 20-step recurrent SNN — r12 VERBATIM (verified 90.3us,
// 48 VGPR, no spill). 256 persistent blocks (1/CU), 16 waves/block, 4
// rows/wave as TWO interleaved pairs. Rank-compacted int byte-offset
// lists, 8-wide ds_read_b64 clusters + exact 4/2/1 tails, no padding.
// Addend order per row: groups 0..3 ascending, j ascending, bias last;
// output layer evens-then-odds — bit-identical to r2/r7.
// ---------------------------------------------------------------------------
__global__ __launch_bounds__(1024) void snn_kernel(
    const float* __restrict__ cur1, const float* __restrict__ W2Tg,
    const float* __restrict__ WoTg, const float* __restrict__ b2,
    const float* __restrict__ bo, const int* __restrict__ nsp,
    float* __restrict__ out) {
  extern __shared__ float lds[];

  const int tid = threadIdx.x;
  {
    float4* dst = (float4*)lds;
    const float4* src = (const float4*)W2Tg;
#pragma unroll
    for (int i = 0; i < 8; ++i) dst[tid + i * 1024] = src[tid + i * 1024];
    if (tid < 320)
      ((float4*)((char*)lds + WOT_OFF))[tid] = ((const float4*)WoTg)[tid];
  }
  __syncthreads();

  const int w = tid >> 6;
  const int l = tid & 63;
  const int lo = (l < NC) ? l : 0;
  const float bb0 = b2[2 * l];
  const float bb1 = b2[2 * l + 1];
  const float bol = bo[lo];
  const int nsteps = *nsp;

  int* scrA = (int*)((char*)lds + SCR_OFF) + w * 256;  // 128 ints
  int* scrB = scrA + 128;                              // 128 ints
  const char* w2b = (const char*)lds + 8 * l;
  const char* wob = (const char*)lds + WOT_OFF + 4 * lo;

  const int wr0 = l << 9;
  const int wr1 = (64 + l) << 9;
  const int wr2 = (128 + l) << 9;
  const int wr3 = (192 + l) << 9;
  const int or0 = 80 * l;
  const int or1 = 80 * l + 40;

#define LOAD8(P, scrp, kk)                                  \
  const int4 P##ia = *(const int4*)((scrp) + (kk));         \
  const int4 P##ib = *(const int4*)((scrp) + (kk) + 4);     \
  const v2f P##p0 = *(const v2f*)(w2b + P##ia.x);           \
  const v2f P##p1 = *(const v2f*)(w2b + P##ia.y);           \
  const v2f P##p2 = *(const v2f*)(w2b + P##ia.z);           \
  const v2f P##p3 = *(const v2f*)(w2b + P##ia.w);           \
  const v2f P##p4 = *(const v2f*)(w2b + P##ib.x);           \
  const v2f P##p5 = *(const v2f*)(w2b + P##ib.y);           \
  const v2f P##p6 = *(const v2f*)(w2b + P##ib.z);           \
  const v2f P##p7 = *(const v2f*)(w2b + P##ib.w);

#define ADD8(P, acc)                                        \
  acc += P##p0; acc += P##p1; acc += P##p2; acc += P##p3;   \
  acc += P##p4; acc += P##p5; acc += P##p6; acc += P##p7;

#define TAILS(scrp, S, acc)                                 \
  {                                                         \
    int k = ((S) >> 3) << 3;                                \
    if ((S) & 4) {                                          \
      const int4 ia = *(const int4*)((scrp) + k);           \
      const v2f p0 = *(const v2f*)(w2b + ia.x);             \
      const v2f p1 = *(const v2f*)(w2b + ia.y);             \
      const v2f p2 = *(const v2f*)(w2b + ia.z);             \
      const v2f p3 = *(const v2f*)(w2b + ia.w);             \
      acc += p0; acc += p1; acc += p2; acc += p3;           \
      k += 4;                                               \
    }                                                       \
    if ((S) & 2) {                                          \
      const int2 ia = *(const int2*)((scrp) + k);           \
      const v2f p0 = *(const v2f*)(w2b + ia.x);             \
      const v2f p1 = *(const v2f*)(w2b + ia.y);             \
      acc += p0; acc += p1;                                 \
      k += 2;                                               \
    }                                                       \
    if ((S) & 1) {                                          \
      const v2f p0 = *(const v2f*)(w2b + (scrp)[k]);        \
      acc += p0;                                            \
    }                                                       \
  }

#define OLOAD8(P, scrp, kk)                                 \
  const int4 P##ia = *(const int4*)((scrp) + (kk));         \
  const int4 P##ib = *(const int4*)((scrp) + (kk) + 4);     \
  const float P##q0 = *(const float*)(wob + P##ia.x);       \
  const float P##q1 = *(const float*)(wob + P##ia.y);       \
  const float P##q2 = *(const float*)(wob + P##ia.z);       \
  const float P##q3 = *(const float*)(wob + P##ia.w);       \
  const float P##q4 = *(const float*)(wob + P##ib.x);       \
  const float P##q5 = *(const float*)(wob + P##ib.y);       \
  const float P##q6 = *(const float*)(wob + P##ib.z);       \
  const float P##q7 = *(const float*)(wob + P##ib.w);

#define OADD8(P, co)                                        \
  co += P##q0; co += P##q1; co += P##q2; co += P##q3;       \
  co += P##q4; co += P##q5; co += P##q6; co += P##q7;

#define OTAILS(scrp, S, co)                                 \
  {                                                         \
    int k = ((S) >> 3) << 3;                                \
    if ((S) & 4) {                                          \
      const int4 ia = *(const int4*)((scrp) + k);           \
      const float u0 = *(const float*)(wob + ia.x);         \
      const float u1 = *(const float*)(wob + ia.y);         \
      const float u2 = *(const float*)(wob + ia.z);         \
      const float u3 = *(const float*)(wob + ia.w);         \
      co += u0; co += u1; co += u2; co += u3;               \
      k += 4;                                               \
    }                                                       \
    if ((S) & 2) {                                          \
      const int2 ia = *(const int2*)((scrp) + k);           \
      const float u0 = *(const float*)(wob + ia.x);         \
      const float u1 = *(const float*)(wob + ia.y);         \
      co += u0; co += u1;                                   \
      k += 2;                                               \
    }                                                       \
    if ((S) & 1) {                                          \
      co += *(const float*)(wob + (scrp)[k]);               \
    }                                                       \
  }

  for (int rp = 0; rp < 2; ++rp) {
    const long bA = (long)blockIdx.x * 64 + w * 4 + rp * 2;
    const long bB = bA + 1;

    float cA[4], cB[4];
#pragma unroll
    for (int i = 0; i < 4; ++i) {
      cA[i] = cur1[bA * H1 + i * 64 + l];
      cB[i] = cur1[bB * H1 + i * 64 + l];
    }

    float mA1[4] = {0.f, 0.f, 0.f, 0.f}, spA1[4] = {0.f, 0.f, 0.f, 0.f};
    float mB1[4] = {0.f, 0.f, 0.f, 0.f}, spB1[4] = {0.f, 0.f, 0.f, 0.f};
    float mA2a = 0.f, mA2b = 0.f, spA2a = 0.f, spA2b = 0.f;
    float mB2a = 0.f, mB2b = 0.f, spB2a = 0.f, spB2b = 0.f;
    float moA = 0.f, spoA = 0.f, cntA = 0.f;
    float moB = 0.f, spoB = 0.f, cntB = 0.f;

    for (int t = 0; t < nsteps; ++t) {
      // ---- layer 1 LIF + spike masks, both rows ----
      unsigned long long gA[4], gB[4];
      bool sA[4], sB[4];
#pragma unroll
      for (int i = 0; i < 4; ++i) {
        mA1[i] = fmaf(0.5f, mA1[i], cA[i]) - spA1[i];
        sA[i] = mA1[i] > 1.0f;
        spA1[i] = sA[i] ? 1.0f : 0.0f;
        gA[i] = __ballot(sA[i]);
        mB1[i] = fmaf(0.5f, mB1[i], cB[i]) - spB1[i];
        sB[i] = mB1[i] > 1.0f;
        spB1[i] = sB[i] ? 1.0f : 0.0f;
        gB[i] = __ballot(sB[i]);
      }
      const int pA0 = (int)__popcll(gA[0]);
      const int pA01 = pA0 + (int)__popcll(gA[1]);
      const int pA012 = pA01 + (int)__popcll(gA[2]);
      const int SA = pA012 + (int)__popcll(gA[3]);
      const int pB0 = (int)__popcll(gB[0]);
      const int pB01 = pB0 + (int)__popcll(gB[1]);
      const int pB012 = pB01 + (int)__popcll(gB[2]);
      const int SB = pB012 + (int)__popcll(gB[3]);

      // ---- build both lists (rank-compacted, j-ascending; capped) ----
      if (sA[0]) scrA[mbcnt64(gA[0])] = wr0;
      if (sA[1]) scrA[pA0 + mbcnt64(gA[1])] = wr1;
      if (sA[2]) { const int rk = pA01 + mbcnt64(gA[2]);
                   if (rk < 128) scrA[rk] = wr2; }
      if (sA[3]) { const int rk = pA012 + mbcnt64(gA[3]);
                   if (rk < 128) scrA[rk] = wr3; }
      if (sB[0]) scrB[mbcnt64(gB[0])] = wr0;
      if (sB[1]) scrB[pB0 + mbcnt64(gB[1])] = wr1;
      if (sB[2]) { const int rk = pB01 + mbcnt64(gB[2]);
                   if (rk < 128) scrB[rk] = wr2; }
      if (sB[3]) { const int rk = pB012 + mbcnt64(gB[3]);
                   if (rk < 128) scrB[rk] = wr3; }
      asm volatile("s_waitcnt lgkmcnt(0)" ::: "memory");

      // ---- cur2: interleaved 8-wide clusters + exact 4/2/1 tails ----
      v2f accA = {0.f, 0.f}, accB = {0.f, 0.f};
      if (__builtin_expect(SA > 128 || SB > 128, 0)) {
        accA = serial_row(gA[0], gA[1], gA[2], gA[3], w2b);
        accB = serial_row(gB[0], gB[1], gB[2], gB[3], w2b);
      } else {
        const int nA8 = SA >> 3;
        const int nB8 = SB >> 3;
        int ka = 0, kb = 0;
        while (ka < nA8 && kb < nB8) {
          { LOAD8(a_, scrA, ka * 8) LOAD8(b_, scrB, kb * 8)
            ADD8(a_, accA) ADD8(b_, accB) }
          ++ka; ++kb;
        }
        while (ka < nA8) {
          { LOAD8(c_, scrA, ka * 8) ADD8(c_, accA) }
          ++ka;
        }
        while (kb < nB8) {
          { LOAD8(d_, scrB, kb * 8) ADD8(d_, accB) }
          ++kb;
        }
        TAILS(scrA, SA, accA)
        TAILS(scrB, SB, accB)
      }
      const float aA0 = accA.x + bb0;
      const float aA1 = accA.y + bb1;
      const float aB0 = accB.x + bb0;
      const float aB1 = accB.y + bb1;

      // ---- layer 2 LIF, both rows ----
      mA2a = fmaf(0.5f, mA2a, aA0) - spA2a;
      mA2b = fmaf(0.5f, mA2b, aA1) - spA2b;
      mB2a = fmaf(0.5f, mB2a, aB0) - spB2a;
      mB2b = fmaf(0.5f, mB2b, aB1) - spB2b;
      const bool saA = mA2a > 1.0f, sbA = mA2b > 1.0f;
      const bool saB = mB2a > 1.0f, sbB = mB2b > 1.0f;
      const unsigned long long mAe = __ballot(saA);
      const unsigned long long mAo = __ballot(sbA);
      const unsigned long long mBe = __ballot(saB);
      const unsigned long long mBo = __ballot(sbB);
      spA2a = saA ? 1.0f : 0.0f;
      spA2b = sbA ? 1.0f : 0.0f;
      spB2a = saB ? 1.0f : 0.0f;
      spB2b = sbB ? 1.0f : 0.0f;
      const int pAe = (int)__popcll(mAe);
      const int SoA = pAe + (int)__popcll(mAo);
      const int pBe = (int)__popcll(mBe);
      const int SoB = pBe + (int)__popcll(mBo);

      // ---- output-layer lists (evens ascending, then odds; max 128) ----
      if (saA) scrA[mbcnt64(mAe)] = or0;
      if (sbA) scrA[pAe + mbcnt64(mAo)] = or1;
      if (saB) scrB[mbcnt64(mBe)] = or0;
      if (sbB) scrB[pBe + mbcnt64(mBo)] = or1;
      asm volatile("s_waitcnt lgkmcnt(0)" ::: "memory");

      float coA = 0.f, coB = 0.f;
      {
        const int nA8 = SoA >> 3;
        const int nB8 = SoB >> 3;
        int ka = 0, kb = 0;
        while (ka < nA8 && kb < nB8) {
          { OLOAD8(e_, scrA, ka * 8) OLOAD8(f_, scrB, kb * 8)
            OADD8(e_, coA) OADD8(f_, coB) }
          ++ka; ++kb;
        }
        while (ka < nA8) {
          { OLOAD8(g_, scrA, ka * 8) OADD8(g_, coA) }
          ++ka;
        }
        while (kb < nB8) {
          { OLOAD8(h_, scrB, kb * 8) OADD8(h_, coB) }
          ++kb;
        }
        OTAILS(scrA, SoA, coA)
        OTAILS(scrB, SoB, coB)
      }
      coA += bol;
      coB += bol;

      // ---- output LIF + spike count, both rows ----
      moA = fmaf(0.5f, moA, coA) - spoA;
      moB = fmaf(0.5f, moB, coB) - spoB;
      const bool soA = moA > 1.0f;
      const bool soB = moB > 1.0f;
      spoA = soA ? 1.0f : 0.0f;
      spoB = soB ? 1.0f : 0.0f;
      cntA += spoA;
      cntB += spoB;
    }

    if (l < NC) {
      out[bA * NC + l] = cntA;
      out[bB * NC + l] = cntB;
    }
  }
#undef LOAD8
#undef ADD8
#undef TAILS
#undef OLOAD8
#undef OADD8
#undef OTAILS
}

// ---------------------------------------------------------------------------
extern "C" void kernel_launch(void* const* d_in, const int* in_sizes, int n_in,
                              void* d_out, int out_size, void* d_ws,
                              size_t ws_size, hipStream_t stream) {
  const float* x  = (const float*)d_in[0];
  const float* W1 = (const float*)d_in[1];
  const float* b1 = (const float*)d_in[2];
  const float* W2 = (const float*)d_in[3];
  const float* b2 = (const float*)d_in[4];
  const float* Wo = (const float*)d_in[5];
  const float* bo = (const float*)d_in[6];
  const int* nsp  = (const int*)d_in[7];
  float* outp = (float*)d_out;

  // ws layout: cur1 (16384*256 f) | W2T (32768 f) | WoT (1280 f)
  float* cur1 = (float*)d_ws;
  float* W2Tg = cur1 + (size_t)B_TOT * H1;
  float* WoTg = W2Tg + H1 * H2;

  gemm1_kernel<<<B_TOT / 16, 256, 0, stream>>>(x, W1, b1, cur1);
  transpose_kernel<<<(H2 * H1 + NC * H2 + 1023) / 1024, 1024, 0, stream>>>(
      W2, Wo, W2Tg, WoTg);

  hipFuncSetAttribute((const void*)snn_kernel,
                      hipFuncAttributeMaxDynamicSharedMemorySize, LDS_BYTES);
  snn_kernel<<<256, 1024, LDS_BYTES, stream>>>(cur1, W2Tg, WoTg, b2, bo, nsp,
                                               outp);
}